// Round 1
// baseline (563.758 us; speedup 1.0000x reference)
//
#include <hip/hip_runtime.h>
#include <hip/hip_bf16.h>
#include <stdint.h>

typedef float f32x4_t __attribute__((ext_vector_type(4)));
typedef short s16x8_t __attribute__((ext_vector_type(8)));

#define LDS_AS __attribute__((address_space(3)))
#define GLB_AS __attribute__((address_space(1)))

__device__ __forceinline__ void gload16(void* lds, const void* g) {
    __builtin_amdgcn_global_load_lds((const GLB_AS uint32_t*)g,
                                     (LDS_AS uint32_t*)lds, 16, 0, 0);
}

// ---------------- RoPE table: cos/sin[s][j], j in [0,64), invf index j&31 ----------------
__global__ __launch_bounds__(256) void rope_table_kernel(float* __restrict__ cos_t,
                                                         float* __restrict__ sin_t) {
    int idx = blockIdx.x * 256 + threadIdx.x;       // 1024*64 exact
    int s = idx >> 6, j = idx & 63;
    float invf = powf(10000.0f, -((float)((j & 31) * 2)) / 64.0f);
    float a = (float)s * invf;
    cos_t[idx] = cosf(a);
    sin_t[idx] = sinf(a);
}

// ---------------- fp32 -> bf16 convert (x4 vectorized) ----------------
__global__ __launch_bounds__(256) void f32_to_bf16_kernel(const float* __restrict__ in,
                                                          __hip_bfloat16* __restrict__ out, int n4) {
    int i = blockIdx.x * 256 + threadIdx.x;
    if (i >= n4) return;
    float4 v = reinterpret_cast<const float4*>(in)[i];
    struct __align__(8) BF4 { __hip_bfloat16 a, b, c, d; } r;
    r.a = __float2bfloat16(v.x); r.b = __float2bfloat16(v.y);
    r.c = __float2bfloat16(v.z); r.d = __float2bfloat16(v.w);
    reinterpret_cast<BF4*>(out)[i] = r;
}

// ---------------- transpose + convert: W[K][N] f32 -> WT[Npad][K] bf16 (zero-pad n>=N) ----
__global__ __launch_bounds__(256) void transpose_convert(const float* __restrict__ W,
                                                         __hip_bfloat16* __restrict__ WT,
                                                         int K, int N, int Npad) {
    __shared__ float tile[32][33];
    int k0 = blockIdx.y * 32, n0 = blockIdx.x * 32;
    int tx = threadIdx.x & 31, ty = threadIdx.x >> 5;   // 32 x 8
#pragma unroll
    for (int i = 0; i < 4; i++) {
        int ky = i * 8 + ty;
        int n = n0 + tx;
        float v = 0.f;
        if (n < N) v = W[(size_t)(k0 + ky) * N + n];
        tile[ky][tx] = v;
    }
    __syncthreads();
#pragma unroll
    for (int i = 0; i < 4; i++) {
        int ny = i * 8 + ty;
        WT[(size_t)(n0 + ny) * K + k0 + tx] = __float2bfloat16(tile[tx][ny]);
    }
}

// ---------------- rmsnorm: in f32 [2048][in_stride] (cols used) -> out bf16 [2048][cols] ----
__global__ __launch_bounds__(256) void rmsnorm_kernel(const float* __restrict__ in,
                                                      const float* __restrict__ g,
                                                      __hip_bfloat16* __restrict__ out,
                                                      int cols, int in_stride) {
    int row = blockIdx.x;
    const float* x = in + (size_t)row * in_stride;
    float ss = 0.f;
    for (int c = threadIdx.x; c < cols; c += 256) { float v = x[c]; ss += v * v; }
#pragma unroll
    for (int off = 32; off > 0; off >>= 1) ss += __shfl_xor(ss, off);
    __shared__ float red[4];
    if ((threadIdx.x & 63) == 0) red[threadIdx.x >> 6] = ss;
    __syncthreads();
    float tot = red[0] + red[1] + red[2] + red[3];
    float rms = sqrtf(tot / (float)cols);
    float inv = 1.0f / (rms + 1e-6f);
    for (int c = threadIdx.x; c < cols; c += 256)
        out[(size_t)row * cols + c] = __float2bfloat16(x[c] * inv * g[c]);
}

// ---------------- k_rope: kv[tok][512..575] f32 -> roped bf16 [tok][64] (no scale) --------
__global__ __launch_bounds__(256) void rope_k_kernel(const float* __restrict__ kv,
                                                     const float* __restrict__ cos_t,
                                                     const float* __restrict__ sin_t,
                                                     __hip_bfloat16* __restrict__ k_rope) {
    int idx = blockIdx.x * 256 + threadIdx.x;       // 2048*32 exact
    int tok = idx >> 5, j = idx & 31;
    int s = tok & 1023;
    const float* x = kv + (size_t)tok * 640 + 512;
    float x1 = x[j], x2 = x[j + 32];
    float co = cos_t[s * 64 + j], si = sin_t[s * 64 + j];
    __hip_bfloat16* o = k_rope + (size_t)tok * 64;
    o[j]      = __float2bfloat16(x1 * co - x2 * si);
    o[j + 32] = __float2bfloat16(x2 * co + x1 * si);
}

// ---------------- q: rope last 64 of each head's 192 + scale ALL by 192^-0.5 (in place) ---
__global__ __launch_bounds__(256) void rope_scale_q_kernel(__hip_bfloat16* __restrict__ q,
                                                           const float* __restrict__ cos_t,
                                                           const float* __restrict__ sin_t) {
    int tok = blockIdx.x;
    int s = tok & 1023;
    __hip_bfloat16* row = q + (size_t)tok * 6144;
    const float scale = 0.07216878364870323f;   // 192^-0.5
    for (int i = threadIdx.x; i < 4096; i += 256) {   // nope part: 32 heads x 128
        int h = i >> 7, d = i & 127;
        int c = h * 192 + d;
        row[c] = __float2bfloat16(__bfloat162float(row[c]) * scale);
    }
    for (int i = threadIdx.x; i < 1024; i += 256) {   // rope pairs: 32 heads x 32
        int h = i >> 5, j = i & 31;
        int c = h * 192 + 128 + j;
        float x1 = __bfloat162float(row[c]), x2 = __bfloat162float(row[c + 32]);
        float co = cos_t[s * 64 + j], si = sin_t[s * 64 + j];
        row[c]      = __float2bfloat16((x1 * co - x2 * si) * scale);
        row[c + 32] = __float2bfloat16((x2 * co + x1 * si) * scale);
    }
}

// ---------------- V transpose: kst[tok][h*256+128..255] -> V_T[bh][vd][1024] -------------
__global__ __launch_bounds__(256) void transpose_v_kernel(const __hip_bfloat16* __restrict__ kst,
                                                          __hip_bfloat16* __restrict__ V_T) {
    __shared__ __hip_bfloat16 t[64][136];
    int bid = blockIdx.x;                 // (b*32+h)*16 + st
    int st = bid & 15, bh = bid >> 4;
    int h = bh & 31, b = bh >> 5;
    int s0 = st * 64;
#pragma unroll
    for (int i = 0; i < 4; i++) {
        int c = i * 256 + threadIdx.x;    // 64 rows x 16 octs
        int r = c >> 4, oct = c & 15;
        *(s16x8_t*)&t[r][oct * 8] =
            *(const s16x8_t*)&kst[(size_t)(b * 1024 + s0 + r) * 8192 + h * 256 + 128 + oct * 8];
    }
    __syncthreads();
#pragma unroll
    for (int i = 0; i < 4; i++) {
        int c = i * 256 + threadIdx.x;    // 128 vd x 8 octs
        int vd = c >> 3, oct = c & 7;
        s16x8_t pk;
#pragma unroll
        for (int e = 0; e < 8; e++) pk[e] = *(const short*)&t[oct * 8 + e][vd];
        *(s16x8_t*)&V_T[((size_t)bh * 128 + vd) * 1024 + s0 + oct * 8] = pk;
    }
}

// ---------------- GEMM: A[M][K] bf16 x BT[N][K] bf16 -> C[M][N] (f32 or bf16) -------------
// 128x128 tile, BK=64, 4 waves (2x2), 16x16x32 MFMA, global_load_lds(16B),
// XOR swizzle oct ^= (row&7) applied on BOTH source permutation and ds_read.
template <int OUT_BF16>
__global__ __launch_bounds__(256, 2) void gemm_bt_128(const __hip_bfloat16* __restrict__ A,
                                                      const __hip_bfloat16* __restrict__ BT,
                                                      void* __restrict__ Cout,
                                                      int M, int N, int K) {
    __shared__ __hip_bfloat16 As[128 * 64];
    __shared__ __hip_bfloat16 Bs[128 * 64];
    const int tid = threadIdx.x;
    const int l = tid & 63, w = tid >> 6;
    const int wr = w >> 1, wc = w & 1;
    const int m0 = blockIdx.y * 128, n0 = blockIdx.x * 128;
    const int lrow = l & 15, lkg = l >> 4;

    f32x4_t acc[4][4];
#pragma unroll
    for (int i = 0; i < 4; i++)
#pragma unroll
        for (int j = 0; j < 4; j++) acc[i][j] = (f32x4_t){0.f, 0.f, 0.f, 0.f};

    for (int k0 = 0; k0 < K; k0 += 64) {
        __syncthreads();
#pragma unroll
        for (int i = 0; i < 4; i++) {
            int s = i * 256 + tid;          // 1024 16B slots per tile
            int row = s >> 3, po = s & 7;
            int lo = po ^ (row & 7);        // logical k-octet for this physical slot
            gload16(&As[s * 8], &A[(size_t)(m0 + row) * K + k0 + lo * 8]);
            gload16(&Bs[s * 8], &BT[(size_t)(n0 + row) * K + k0 + lo * 8]);
        }
        __syncthreads();
#pragma unroll
        for (int ks = 0; ks < 2; ks++) {
            s16x8_t a[4], b[4];
#pragma unroll
            for (int m = 0; m < 4; m++) {
                int row = wr * 64 + m * 16 + lrow;
                int oct = (ks * 4 + lkg) ^ (row & 7);
                a[m] = *(const s16x8_t*)&As[row * 64 + oct * 8];
            }
#pragma unroll
            for (int n = 0; n < 4; n++) {
                int row = wc * 64 + n * 16 + lrow;
                int oct = (ks * 4 + lkg) ^ (row & 7);
                b[n] = *(const s16x8_t*)&Bs[row * 64 + oct * 8];
            }
#pragma unroll
            for (int m = 0; m < 4; m++)
#pragma unroll
                for (int n = 0; n < 4; n++)
                    acc[m][n] = __builtin_amdgcn_mfma_f32_16x16x32_bf16(a[m], b[n], acc[m][n], 0, 0, 0);
        }
    }
#pragma unroll
    for (int m = 0; m < 4; m++) {
        int row = m0 + wr * 64 + m * 16 + lkg * 4;
#pragma unroll
        for (int n = 0; n < 4; n++) {
            int col = n0 + wc * 64 + n * 16 + lrow;
#pragma unroll
            for (int r = 0; r < 4; r++) {
                float v = acc[m][n][r];
                if (OUT_BF16)
                    ((__hip_bfloat16*)Cout)[(size_t)(row + r) * N + col] = __float2bfloat16(v);
                else
                    ((float*)Cout)[(size_t)(row + r) * N + col] = v;
            }
        }
    }
}

// ---------------- attention: flash-style, 64 q rows / block, 4 waves x 16 rows -----------
// q: [2048][6144] bf16 (roped+scaled), kst: [2048][8192] bf16 (k_nope cols h*256..+127),
// k_rope: [2048][64] bf16, V_T: [64][128][1024] bf16, attn_out: [2048][4096] bf16
__global__ __launch_bounds__(256, 2) void attn_kernel(const __hip_bfloat16* __restrict__ q,
                                                      const __hip_bfloat16* __restrict__ kst,
                                                      const __hip_bfloat16* __restrict__ k_rope,
                                                      const __hip_bfloat16* __restrict__ V_T,
                                                      __hip_bfloat16* __restrict__ attn_out) {
    __shared__ __hip_bfloat16 Ks[64 * 200];   // [64 kv][192 used, pad->200]
    __shared__ __hip_bfloat16 Vs[128 * 72];   // [128 vd][64 kv, pad->72]
    __shared__ __hip_bfloat16 Ps[64 * 72];    // [64 q ][64 kv, pad->72]
    int bid = blockIdx.x;                 // (b*32+h)*16 + qt
    int qt = bid & 15, bh = bid >> 4;
    int h = bh & 31, b = bh >> 5;
    int q0 = qt * 64;
    int tid = threadIdx.x, l = tid & 63, w = tid >> 6;
    int lrow = l & 15, lkg = l >> 4;

    // Q fragments in registers: wave w owns q rows q0 + w*16 .. +15
    s16x8_t qa[6];
    {
        size_t qbase = (size_t)(b * 1024 + q0 + w * 16 + lrow) * 6144 + h * 192;
#pragma unroll
        for (int f = 0; f < 6; f++)
            qa[f] = *(const s16x8_t*)&q[qbase + f * 32 + lkg * 8];
    }
    f32x4_t acc_o[8];
#pragma unroll
    for (int n = 0; n < 8; n++) acc_o[n] = (f32x4_t){0.f, 0.f, 0.f, 0.f};
    float m_run[4] = {-1e30f, -1e30f, -1e30f, -1e30f};
    float l_run[4] = {0.f, 0.f, 0.f, 0.f};

    for (int kt = 0; kt < 16; kt++) {
        int kv0 = kt * 64;
        __syncthreads();
        // stage K tile (k_nope from kst + roped k_rope): 64 rows x 24 octets
#pragma unroll
        for (int it = 0; it < 6; it++) {
            int c = it * 256 + tid;
            int r = c / 24, oct = c % 24;
            const __hip_bfloat16* src =
                (oct < 16) ? &kst[(size_t)(b * 1024 + kv0 + r) * 8192 + h * 256 + oct * 8]
                           : &k_rope[(size_t)(b * 1024 + kv0 + r) * 64 + (oct - 16) * 8];
            *(s16x8_t*)&Ks[r * 200 + oct * 8] = *(const s16x8_t*)src;
        }
        // stage V^T tile: 128 vd x 8 octets
#pragma unroll
        for (int it = 0; it < 4; it++) {
            int c = it * 256 + tid;
            int vd = c >> 3, oct = c & 7;
            *(s16x8_t*)&Vs[vd * 72 + oct * 8] =
                *(const s16x8_t*)&V_T[((size_t)bh * 128 + vd) * 1024 + kv0 + oct * 8];
        }
        __syncthreads();
        // QK^T (pre-scaled): sc[c] = 16 q-rows x 16 kv-cols, c = kv col block
        f32x4_t sc[4];
#pragma unroll
        for (int c = 0; c < 4; c++) sc[c] = (f32x4_t){0.f, 0.f, 0.f, 0.f};
#pragma unroll
        for (int f = 0; f < 6; f++)
#pragma unroll
            for (int c = 0; c < 4; c++) {
                s16x8_t kb = *(const s16x8_t*)&Ks[(c * 16 + lrow) * 200 + f * 32 + lkg * 8];
                sc[c] = __builtin_amdgcn_mfma_f32_16x16x32_bf16(qa[f], kb, sc[c], 0, 0, 0);
            }
        // online softmax; each lane owns rows lkg*4 + r, 16 lanes of group share them
        float p[4][4];
#pragma unroll
        for (int r = 0; r < 4; r++) {
            float mx = fmaxf(fmaxf(sc[0][r], sc[1][r]), fmaxf(sc[2][r], sc[3][r]));
#pragma unroll
            for (int off = 1; off < 16; off <<= 1) mx = fmaxf(mx, __shfl_xor(mx, off));
            float mn = fmaxf(m_run[r], mx);
            float al = __expf(m_run[r] - mn);
            m_run[r] = mn;
            float sum = 0.f;
#pragma unroll
            for (int c = 0; c < 4; c++) {
                float pv = __expf(sc[c][r] - mn);
                p[c][r] = pv;
                sum += pv;
            }
#pragma unroll
            for (int off = 1; off < 16; off <<= 1) sum += __shfl_xor(sum, off);
            l_run[r] = l_run[r] * al + sum;
#pragma unroll
            for (int n = 0; n < 8; n++) acc_o[n][r] *= al;
        }
        // P -> LDS (wave-private rows w*16..+15), then PV
#pragma unroll
        for (int c = 0; c < 4; c++)
#pragma unroll
            for (int r = 0; r < 4; r++)
                Ps[(w * 16 + lkg * 4 + r) * 72 + c * 16 + lrow] = __float2bfloat16(p[c][r]);
        asm volatile("s_waitcnt lgkmcnt(0)" ::: "memory");
#pragma unroll
        for (int kk = 0; kk < 2; kk++) {
            s16x8_t pa = *(const s16x8_t*)&Ps[(w * 16 + lrow) * 72 + kk * 32 + lkg * 8];
#pragma unroll
            for (int n = 0; n < 8; n++) {
                s16x8_t vb = *(const s16x8_t*)&Vs[(n * 16 + lrow) * 72 + kk * 32 + lkg * 8];
                acc_o[n] = __builtin_amdgcn_mfma_f32_16x16x32_bf16(pa, vb, acc_o[n], 0, 0, 0);
            }
        }
    }
    // epilogue: O /= l, write bf16
#pragma unroll
    for (int r = 0; r < 4; r++) {
        float inv = 1.0f / l_run[r];
        size_t tok = (size_t)(b * 1024 + q0 + w * 16 + lkg * 4 + r);
#pragma unroll
        for (int n = 0; n < 8; n++)
            attn_out[tok * 4096 + h * 128 + n * 16 + lrow] =
                __float2bfloat16(acc_o[n][r] * inv);
    }
}

extern "C" void kernel_launch(void* const* d_in, const int* in_sizes, int n_in,
                              void* d_out, int out_size, void* d_ws, size_t ws_size,
                              hipStream_t stream) {
    const float* hidden = (const float*)d_in[0];
    const float* w_qa   = (const float*)d_in[1];
    const float* g_qa   = (const float*)d_in[2];
    const float* w_qb   = (const float*)d_in[3];
    const float* w_kva  = (const float*)d_in[4];
    const float* g_kva  = (const float*)d_in[5];
    const float* w_kvb  = (const float*)d_in[6];
    const float* w_o    = (const float*)d_in[7];
    float* out = (float*)d_out;

    char* base = (char*)d_ws;
    size_t off = 0;
    auto alloc = [&](size_t bytes) -> void* {
        off = (off + 255) & ~(size_t)255;
        void* p = base + off;
        off += bytes;
        return p;
    };
    float* cos_t = (float*)alloc(1024 * 64 * 4);
    float* sin_t = (float*)alloc(1024 * 64 * 4);
    __hip_bfloat16* hid_b  = (__hip_bfloat16*)alloc(2048ull * 4096 * 2);  // later reused as V_T
    __hip_bfloat16* wqaT   = (__hip_bfloat16*)alloc(1536ull * 4096 * 2);
    __hip_bfloat16* wqbT   = (__hip_bfloat16*)alloc(6144ull * 1536 * 2);  // later reused as attn_out
    __hip_bfloat16* wkvaT  = (__hip_bfloat16*)alloc(640ull * 4096 * 2);
    __hip_bfloat16* wkvbT  = (__hip_bfloat16*)alloc(8192ull * 512 * 2);
    __hip_bfloat16* woT    = (__hip_bfloat16*)alloc(4096ull * 4096 * 2);
    float* q_a             = (float*)alloc(2048ull * 1536 * 4);
    __hip_bfloat16* q_c    = (__hip_bfloat16*)alloc(2048ull * 1536 * 2);
    __hip_bfloat16* q_buf  = (__hip_bfloat16*)alloc(2048ull * 6144 * 2);
    float* kv              = (float*)alloc(2048ull * 640 * 4);
    __hip_bfloat16* k_c    = (__hip_bfloat16*)alloc(2048ull * 512 * 2);
    __hip_bfloat16* k_rope = (__hip_bfloat16*)alloc(2048ull * 64 * 2);
    __hip_bfloat16* kst    = (__hip_bfloat16*)alloc(2048ull * 8192 * 2);
    __hip_bfloat16* V_T      = hid_b;   // hid_b dead after the two first GEMMs
    __hip_bfloat16* attn_out = wqbT;    // wqbT dead after q GEMM

    rope_table_kernel<<<256, 256, 0, stream>>>(cos_t, sin_t);
    f32_to_bf16_kernel<<<8192, 256, 0, stream>>>(hidden, hid_b, 2048 * 4096 / 4);
    transpose_convert<<<dim3(1536 / 32, 4096 / 32), 256, 0, stream>>>(w_qa, wqaT, 4096, 1536, 1536);
    transpose_convert<<<dim3(640 / 32, 4096 / 32), 256, 0, stream>>>(w_kva, wkvaT, 4096, 576, 640);
    transpose_convert<<<dim3(6144 / 32, 1536 / 32), 256, 0, stream>>>(w_qb, wqbT, 1536, 6144, 6144);
    transpose_convert<<<dim3(8192 / 32, 512 / 32), 256, 0, stream>>>(w_kvb, wkvbT, 512, 8192, 8192);
    transpose_convert<<<dim3(4096 / 32, 4096 / 32), 256, 0, stream>>>(w_o, woT, 4096, 4096, 4096);

    gemm_bt_128<0><<<dim3(1536 / 128, 16), 256, 0, stream>>>(hid_b, wqaT, q_a, 2048, 1536, 4096);
    gemm_bt_128<0><<<dim3(640 / 128, 16), 256, 0, stream>>>(hid_b, wkvaT, kv, 2048, 640, 4096);
    rmsnorm_kernel<<<2048, 256, 0, stream>>>(q_a, g_qa, q_c, 1536, 1536);
    rmsnorm_kernel<<<2048, 256, 0, stream>>>(kv, g_kva, k_c, 512, 640);
    rope_k_kernel<<<2048 * 32 / 256, 256, 0, stream>>>(kv, cos_t, sin_t, k_rope);
    gemm_bt_128<1><<<dim3(6144 / 128, 16), 256, 0, stream>>>(q_c, wqbT, q_buf, 2048, 6144, 1536);
    rope_scale_q_kernel<<<2048, 256, 0, stream>>>(q_buf, cos_t, sin_t);
    gemm_bt_128<1><<<dim3(8192 / 128, 16), 256, 0, stream>>>(k_c, wkvbT, kst, 2048, 8192, 512);
    transpose_v_kernel<<<1024, 256, 0, stream>>>(kst, V_T);
    attn_kernel<<<1024, 256, 0, stream>>>(q_buf, kst, k_rope, V_T, attn_out);
    gemm_bt_128<0><<<dim3(4096 / 128, 16), 256, 0, stream>>>(attn_out, woT, out, 2048, 4096, 4096);
}

// Round 2
// 538.383 us; speedup vs baseline: 1.0471x; 1.0471x over previous
//
#include <hip/hip_runtime.h>
#include <hip/hip_bf16.h>
#include <stdint.h>

typedef float f32x4_t __attribute__((ext_vector_type(4)));
typedef short s16x8_t __attribute__((ext_vector_type(8)));

#define LDS_AS __attribute__((address_space(3)))
#define GLB_AS __attribute__((address_space(1)))

__device__ __forceinline__ void gload16(void* lds, const void* g) {
    __builtin_amdgcn_global_load_lds((const GLB_AS uint32_t*)g,
                                     (LDS_AS uint32_t*)lds, 16, 0, 0);
}

// ---------------- RoPE table: cos/sin[s][j], j in [0,64), invf index j&31 ----------------
__global__ __launch_bounds__(256) void rope_table_kernel(float* __restrict__ cos_t,
                                                         float* __restrict__ sin_t) {
    int idx = blockIdx.x * 256 + threadIdx.x;       // 1024*64 exact
    int s = idx >> 6, j = idx & 63;
    float invf = powf(10000.0f, -((float)((j & 31) * 2)) / 64.0f);
    float a = (float)s * invf;
    cos_t[idx] = cosf(a);
    sin_t[idx] = sinf(a);
}

// ---------------- fp32 -> bf16 convert (x4 vectorized) ----------------
__global__ __launch_bounds__(256) void f32_to_bf16_kernel(const float* __restrict__ in,
                                                          __hip_bfloat16* __restrict__ out, int n4) {
    int i = blockIdx.x * 256 + threadIdx.x;
    if (i >= n4) return;
    float4 v = reinterpret_cast<const float4*>(in)[i];
    struct __align__(8) BF4 { __hip_bfloat16 a, b, c, d; } r;
    r.a = __float2bfloat16(v.x); r.b = __float2bfloat16(v.y);
    r.c = __float2bfloat16(v.z); r.d = __float2bfloat16(v.w);
    reinterpret_cast<BF4*>(out)[i] = r;
}

// ---------------- transpose + convert: W[K][N] f32 -> WT[Npad][K] bf16 (zero-pad n>=N) ----
__global__ __launch_bounds__(256) void transpose_convert(const float* __restrict__ W,
                                                         __hip_bfloat16* __restrict__ WT,
                                                         int K, int N, int Npad) {
    __shared__ float tile[32][33];
    int k0 = blockIdx.y * 32, n0 = blockIdx.x * 32;
    int tx = threadIdx.x & 31, ty = threadIdx.x >> 5;   // 32 x 8
#pragma unroll
    for (int i = 0; i < 4; i++) {
        int ky = i * 8 + ty;
        int n = n0 + tx;
        float v = 0.f;
        if (n < N) v = W[(size_t)(k0 + ky) * N + n];
        tile[ky][tx] = v;
    }
    __syncthreads();
#pragma unroll
    for (int i = 0; i < 4; i++) {
        int ny = i * 8 + ty;
        WT[(size_t)(n0 + ny) * K + k0 + tx] = __float2bfloat16(tile[tx][ny]);
    }
}

// ---------------- rmsnorm: in f32 [2048][in_stride] (cols used) -> out bf16 [2048][cols] ----
__global__ __launch_bounds__(256) void rmsnorm_kernel(const float* __restrict__ in,
                                                      const float* __restrict__ g,
                                                      __hip_bfloat16* __restrict__ out,
                                                      int cols, int in_stride) {
    int row = blockIdx.x;
    const float* x = in + (size_t)row * in_stride;
    float ss = 0.f;
    for (int c = threadIdx.x; c < cols; c += 256) { float v = x[c]; ss += v * v; }
#pragma unroll
    for (int off = 32; off > 0; off >>= 1) ss += __shfl_xor(ss, off);
    __shared__ float red[4];
    if ((threadIdx.x & 63) == 0) red[threadIdx.x >> 6] = ss;
    __syncthreads();
    float tot = red[0] + red[1] + red[2] + red[3];
    float rms = sqrtf(tot / (float)cols);
    float inv = 1.0f / (rms + 1e-6f);
    for (int c = threadIdx.x; c < cols; c += 256)
        out[(size_t)row * cols + c] = __float2bfloat16(x[c] * inv * g[c]);
}

// ---------------- k_rope: kv[tok][512..575] f32 -> roped bf16 [tok][64] (no scale) --------
__global__ __launch_bounds__(256) void rope_k_kernel(const float* __restrict__ kv,
                                                     const float* __restrict__ cos_t,
                                                     const float* __restrict__ sin_t,
                                                     __hip_bfloat16* __restrict__ k_rope) {
    int idx = blockIdx.x * 256 + threadIdx.x;       // 2048*32 exact
    int tok = idx >> 5, j = idx & 31;
    int s = tok & 1023;
    const float* x = kv + (size_t)tok * 640 + 512;
    float x1 = x[j], x2 = x[j + 32];
    float co = cos_t[s * 64 + j], si = sin_t[s * 64 + j];
    __hip_bfloat16* o = k_rope + (size_t)tok * 64;
    o[j]      = __float2bfloat16(x1 * co - x2 * si);
    o[j + 32] = __float2bfloat16(x2 * co + x1 * si);
}

// ---------------- q: rope last 64 of each head's 192 + scale ALL by 192^-0.5 (in place) ---
__global__ __launch_bounds__(256) void rope_scale_q_kernel(__hip_bfloat16* __restrict__ q,
                                                           const float* __restrict__ cos_t,
                                                           const float* __restrict__ sin_t) {
    int tok = blockIdx.x;
    int s = tok & 1023;
    __hip_bfloat16* row = q + (size_t)tok * 6144;
    const float scale = 0.07216878364870323f;   // 192^-0.5
    for (int i = threadIdx.x; i < 4096; i += 256) {   // nope part: 32 heads x 128
        int h = i >> 7, d = i & 127;
        int c = h * 192 + d;
        row[c] = __float2bfloat16(__bfloat162float(row[c]) * scale);
    }
    for (int i = threadIdx.x; i < 1024; i += 256) {   // rope pairs: 32 heads x 32
        int h = i >> 5, j = i & 31;
        int c = h * 192 + 128 + j;
        float x1 = __bfloat162float(row[c]), x2 = __bfloat162float(row[c + 32]);
        float co = cos_t[s * 64 + j], si = sin_t[s * 64 + j];
        row[c]      = __float2bfloat16((x1 * co - x2 * si) * scale);
        row[c + 32] = __float2bfloat16((x2 * co + x1 * si) * scale);
    }
}

// ---------------- V transpose: kst[tok][h*256+128..255] -> V_T[bh][vd][1024] -------------
__global__ __launch_bounds__(256) void transpose_v_kernel(const __hip_bfloat16* __restrict__ kst,
                                                          __hip_bfloat16* __restrict__ V_T) {
    __shared__ __hip_bfloat16 t[64][136];
    int bid = blockIdx.x;                 // (b*32+h)*16 + st
    int st = bid & 15, bh = bid >> 4;
    int h = bh & 31, b = bh >> 5;
    int s0 = st * 64;
#pragma unroll
    for (int i = 0; i < 4; i++) {
        int c = i * 256 + threadIdx.x;    // 64 rows x 16 octs
        int r = c >> 4, oct = c & 15;
        *(s16x8_t*)&t[r][oct * 8] =
            *(const s16x8_t*)&kst[(size_t)(b * 1024 + s0 + r) * 8192 + h * 256 + 128 + oct * 8];
    }
    __syncthreads();
#pragma unroll
    for (int i = 0; i < 4; i++) {
        int c = i * 256 + threadIdx.x;    // 128 vd x 8 octs
        int vd = c >> 3, oct = c & 7;
        s16x8_t pk;
#pragma unroll
        for (int e = 0; e < 8; e++) pk[e] = *(const short*)&t[oct * 8 + e][vd];
        *(s16x8_t*)&V_T[((size_t)bh * 128 + vd) * 1024 + s0 + oct * 8] = pk;
    }
}

// ---------------- GEMM: A[M][K] bf16 x BT[N][K] bf16 -> C[M][N] (f32 or bf16) -------------
template <int OUT_BF16>
__global__ __launch_bounds__(256, 2) void gemm_bt_128(const __hip_bfloat16* __restrict__ A,
                                                      const __hip_bfloat16* __restrict__ BT,
                                                      void* __restrict__ Cout,
                                                      int M, int N, int K) {
    __shared__ __hip_bfloat16 As[128 * 64];
    __shared__ __hip_bfloat16 Bs[128 * 64];
    const int tid = threadIdx.x;
    const int l = tid & 63, w = tid >> 6;
    const int wr = w >> 1, wc = w & 1;
    const int m0 = blockIdx.y * 128, n0 = blockIdx.x * 128;
    const int lrow = l & 15, lkg = l >> 4;

    f32x4_t acc[4][4];
#pragma unroll
    for (int i = 0; i < 4; i++)
#pragma unroll
        for (int j = 0; j < 4; j++) acc[i][j] = (f32x4_t){0.f, 0.f, 0.f, 0.f};

    for (int k0 = 0; k0 < K; k0 += 64) {
        __syncthreads();
#pragma unroll
        for (int i = 0; i < 4; i++) {
            int s = i * 256 + tid;          // 1024 16B slots per tile
            int row = s >> 3, po = s & 7;
            int lo = po ^ (row & 7);        // logical k-octet for this physical slot
            gload16(&As[s * 8], &A[(size_t)(m0 + row) * K + k0 + lo * 8]);
            gload16(&Bs[s * 8], &BT[(size_t)(n0 + row) * K + k0 + lo * 8]);
        }
        __syncthreads();
#pragma unroll
        for (int ks = 0; ks < 2; ks++) {
            s16x8_t a[4], b[4];
#pragma unroll
            for (int m = 0; m < 4; m++) {
                int row = wr * 64 + m * 16 + lrow;
                int oct = (ks * 4 + lkg) ^ (row & 7);
                a[m] = *(const s16x8_t*)&As[row * 64 + oct * 8];
            }
#pragma unroll
            for (int n = 0; n < 4; n++) {
                int row = wc * 64 + n * 16 + lrow;
                int oct = (ks * 4 + lkg) ^ (row & 7);
                b[n] = *(const s16x8_t*)&Bs[row * 64 + oct * 8];
            }
#pragma unroll
            for (int m = 0; m < 4; m++)
#pragma unroll
                for (int n = 0; n < 4; n++)
                    acc[m][n] = __builtin_amdgcn_mfma_f32_16x16x32_bf16(a[m], b[n], acc[m][n], 0, 0, 0);
        }
    }
#pragma unroll
    for (int m = 0; m < 4; m++) {
        int row = m0 + wr * 64 + m * 16 + lkg * 4;
#pragma unroll
        for (int n = 0; n < 4; n++) {
            int col = n0 + wc * 64 + n * 16 + lrow;
#pragma unroll
            for (int r = 0; r < 4; r++) {
                float v = acc[m][n][r];
                if (OUT_BF16)
                    ((__hip_bfloat16*)Cout)[(size_t)(row + r) * N + col] = __float2bfloat16(v);
                else
                    ((float*)Cout)[(size_t)(row + r) * N + col] = v;
            }
        }
    }
}

// ---------------- attention v2: 2-phase pipelined K staging, direct-V, T2/T5/T13 ---------
// Block = 64 q rows of one (b,h); 4 waves x 16 rows. KV tiles of 64, 16 iters.
// Ks: double-buffered, global_load_lds, XOR-swizzled (po = oct ^ (row&7)) both sides.
// V^T fragments read direct from global (L2-hot via XCD swizzle). P via wave-private LDS.
__global__ __launch_bounds__(256, 2) void attn2_kernel(const __hip_bfloat16* __restrict__ q,
                                                       const __hip_bfloat16* __restrict__ kst,
                                                       const __hip_bfloat16* __restrict__ k_rope,
                                                       const __hip_bfloat16* __restrict__ V_T,
                                                       __hip_bfloat16* __restrict__ attn_out) {
    __shared__ __align__(16) __hip_bfloat16 Ks[2][64 * 192];  // 2 x 24 KB, swizzled
    __shared__ __align__(16) __hip_bfloat16 Ps[64 * 72];      // 9 KB

    // XCD-bijective swizzle: all 16 q-tiles of one (b,h) land on the same XCD (i%8 const).
    int i = blockIdx.x;                       // grid 1024
    int bh = (i & 7) * 8 + ((i >> 3) & 7);
    int qt = i >> 6;
    int h = bh & 31, b = bh >> 5;
    int q0 = qt * 64;
    int tid = threadIdx.x, l = tid & 63, w = tid >> 6;
    int lrow = l & 15, lkg = l >> 4;

    // Q fragments: wave w owns q rows q0 + w*16 .. +15
    s16x8_t qa[6];
    {
        size_t qbase = (size_t)(b * 1024 + q0 + w * 16 + lrow) * 6144 + h * 192;
#pragma unroll
        for (int f = 0; f < 6; f++)
            qa[f] = *(const s16x8_t*)&q[qbase + f * 32 + lkg * 8];
    }
    f32x4_t acc_o[8];
#pragma unroll
    for (int n = 0; n < 8; n++) acc_o[n] = (f32x4_t){0.f, 0.f, 0.f, 0.f};
    float m_run[4] = {-1e30f, -1e30f, -1e30f, -1e30f};
    float l_run[4] = {0.f, 0.f, 0.f, 0.f};

    size_t krow_base = (size_t)(b * 1024) * 8192 + h * 256;   // kst row base for this head
    size_t rrow_base = (size_t)(b * 1024) * 64;               // k_rope row base

    // stage K tile kv0 into buffer buf: 64 rows x 24 octets, linear LDS dest,
    // inverse-swizzled global source (lo = po ^ (row&7)).
    auto stage_k = [&](int kv0, int buf) {
#pragma unroll
        for (int it = 0; it < 6; it++) {
            int s = it * 256 + tid;               // 0..1535
            int row = s / 24, po = s - row * 24;
            int lo = po ^ (row & 7);
            const __hip_bfloat16* src = (lo < 16)
                ? &kst[krow_base + (size_t)(kv0 + row) * 8192 + lo * 8]
                : &k_rope[rrow_base + (size_t)(kv0 + row) * 64 + (lo - 16) * 8];
            gload16(&Ks[buf][s * 8], src);
        }
    };

    stage_k(0, 0);
    asm volatile("s_waitcnt vmcnt(0)" ::: "memory");
    __syncthreads();

    int cur = 0;
    for (int kt = 0; kt < 16; kt++) {
        int kv0 = kt * 64;
        if (kt < 15) stage_k(kv0 + 64, cur ^ 1);   // prefetch next tile (2-phase)

        // ---- QK^T from Ks[cur] (swizzled ds_read) ----
        f32x4_t sc[4];
#pragma unroll
        for (int c = 0; c < 4; c++) sc[c] = (f32x4_t){0.f, 0.f, 0.f, 0.f};
        __builtin_amdgcn_s_setprio(1);
#pragma unroll
        for (int c = 0; c < 4; c++) {
            int row = c * 16 + lrow;
#pragma unroll
            for (int f = 0; f < 6; f++) {
                int po = ((f * 4 + lkg) ^ (lrow & 7)) * 8;
                s16x8_t kb = *(const s16x8_t*)&Ks[cur][row * 192 + po];
                sc[c] = __builtin_amdgcn_mfma_f32_16x16x32_bf16(qa[f], kb, sc[c], 0, 0, 0);
            }
        }
        __builtin_amdgcn_s_setprio(0);

        // ---- issue V fragment loads early (hide L2 latency under softmax) ----
        s16x8_t vb[2][8];
#pragma unroll
        for (int kk = 0; kk < 2; kk++)
#pragma unroll
            for (int n = 0; n < 8; n++)
                vb[kk][n] = *(const s16x8_t*)&V_T[((size_t)(bh * 128 + n * 16 + lrow)) * 1024 +
                                                  kv0 + kk * 32 + lkg * 8];

        // ---- online softmax (rows lkg*4+r), T13 defer-max ----
        float mx[4];
#pragma unroll
        for (int r = 0; r < 4; r++) {
            float m0 = fmaxf(fmaxf(sc[0][r], sc[1][r]), fmaxf(sc[2][r], sc[3][r]));
#pragma unroll
            for (int off = 1; off < 16; off <<= 1) m0 = fmaxf(m0, __shfl_xor(m0, off));
            mx[r] = m0;
        }
        int small = (mx[0] - m_run[0] <= 8.0f) && (mx[1] - m_run[1] <= 8.0f) &&
                    (mx[2] - m_run[2] <= 8.0f) && (mx[3] - m_run[3] <= 8.0f);
        if (!__all(small)) {
#pragma unroll
            for (int r = 0; r < 4; r++) {
                float mn = fmaxf(m_run[r], mx[r]);
                float al = __expf(m_run[r] - mn);
                m_run[r] = mn;
                l_run[r] *= al;
#pragma unroll
                for (int n = 0; n < 8; n++) acc_o[n][r] *= al;
            }
        }
        float p[4][4];
#pragma unroll
        for (int r = 0; r < 4; r++) {
            float sum = 0.f;
#pragma unroll
            for (int c = 0; c < 4; c++) {
                float pv = __expf(sc[c][r] - m_run[r]);
                p[c][r] = pv;
                sum += pv;
            }
#pragma unroll
            for (int off = 1; off < 16; off <<= 1) sum += __shfl_xor(sum, off);
            l_run[r] += sum;
        }

        // ---- P -> wave-private LDS, then PV with preloaded V fragments ----
#pragma unroll
        for (int c = 0; c < 4; c++)
#pragma unroll
            for (int r = 0; r < 4; r++)
                Ps[(w * 16 + lkg * 4 + r) * 72 + c * 16 + lrow] = __float2bfloat16(p[c][r]);
        asm volatile("s_waitcnt lgkmcnt(0)" ::: "memory");
        __builtin_amdgcn_s_setprio(1);
#pragma unroll
        for (int kk = 0; kk < 2; kk++) {
            s16x8_t pa = *(const s16x8_t*)&Ps[(w * 16 + lrow) * 72 + kk * 32 + lkg * 8];
#pragma unroll
            for (int n = 0; n < 8; n++)
                acc_o[n] = __builtin_amdgcn_mfma_f32_16x16x32_bf16(pa, vb[kk][n], acc_o[n], 0, 0, 0);
        }
        __builtin_amdgcn_s_setprio(0);

        asm volatile("s_waitcnt vmcnt(0)" ::: "memory");
        __syncthreads();
        cur ^= 1;
    }
    // epilogue: O /= l, write bf16
#pragma unroll
    for (int r = 0; r < 4; r++) {
        float inv = 1.0f / l_run[r];
        size_t tok = (size_t)(b * 1024 + q0 + w * 16 + lkg * 4 + r);
#pragma unroll
        for (int n = 0; n < 8; n++)
            attn_out[tok * 4096 + h * 128 + n * 16 + lrow] =
                __float2bfloat16(acc_o[n][r] * inv);
    }
}

extern "C" void kernel_launch(void* const* d_in, const int* in_sizes, int n_in,
                              void* d_out, int out_size, void* d_ws, size_t ws_size,
                              hipStream_t stream) {
    const float* hidden = (const float*)d_in[0];
    const float* w_qa   = (const float*)d_in[1];
    const float* g_qa   = (const float*)d_in[2];
    const float* w_qb   = (const float*)d_in[3];
    const float* w_kva  = (const float*)d_in[4];
    const float* g_kva  = (const float*)d_in[5];
    const float* w_kvb  = (const float*)d_in[6];
    const float* w_o    = (const float*)d_in[7];
    float* out = (float*)d_out;

    char* base = (char*)d_ws;
    size_t off = 0;
    auto alloc = [&](size_t bytes) -> void* {
        off = (off + 255) & ~(size_t)255;
        void* p = base + off;
        off += bytes;
        return p;
    };
    float* cos_t = (float*)alloc(1024 * 64 * 4);
    float* sin_t = (float*)alloc(1024 * 64 * 4);
    __hip_bfloat16* hid_b  = (__hip_bfloat16*)alloc(2048ull * 4096 * 2);  // later reused as V_T
    __hip_bfloat16* wqaT   = (__hip_bfloat16*)alloc(1536ull * 4096 * 2);
    __hip_bfloat16* wqbT   = (__hip_bfloat16*)alloc(6144ull * 1536 * 2);  // later reused as attn_out
    __hip_bfloat16* wkvaT  = (__hip_bfloat16*)alloc(640ull * 4096 * 2);
    __hip_bfloat16* wkvbT  = (__hip_bfloat16*)alloc(8192ull * 512 * 2);
    __hip_bfloat16* woT    = (__hip_bfloat16*)alloc(4096ull * 4096 * 2);
    float* q_a             = (float*)alloc(2048ull * 1536 * 4);
    __hip_bfloat16* q_c    = (__hip_bfloat16*)alloc(2048ull * 1536 * 2);
    __hip_bfloat16* q_buf  = (__hip_bfloat16*)alloc(2048ull * 6144 * 2);
    float* kv              = (float*)alloc(2048ull * 640 * 4);
    __hip_bfloat16* k_c    = (__hip_bfloat16*)alloc(2048ull * 512 * 2);
    __hip_bfloat16* k_rope = (__hip_bfloat16*)alloc(2048ull * 64 * 2);
    __hip_bfloat16* kst    = (__hip_bfloat16*)alloc(2048ull * 8192 * 2);
    __hip_bfloat16* V_T      = hid_b;   // hid_b dead after the two first GEMMs
    __hip_bfloat16* attn_out = wqbT;    // wqbT dead after q GEMM

    rope_table_kernel<<<256, 256, 0, stream>>>(cos_t, sin_t);
    f32_to_bf16_kernel<<<8192, 256, 0, stream>>>(hidden, hid_b, 2048 * 4096 / 4);
    transpose_convert<<<dim3(1536 / 32, 4096 / 32), 256, 0, stream>>>(w_qa, wqaT, 4096, 1536, 1536);
    transpose_convert<<<dim3(640 / 32, 4096 / 32), 256, 0, stream>>>(w_kva, wkvaT, 4096, 576, 640);
    transpose_convert<<<dim3(6144 / 32, 1536 / 32), 256, 0, stream>>>(w_qb, wqbT, 1536, 6144, 6144);
    transpose_convert<<<dim3(8192 / 32, 512 / 32), 256, 0, stream>>>(w_kvb, wkvbT, 512, 8192, 8192);
    transpose_convert<<<dim3(4096 / 32, 4096 / 32), 256, 0, stream>>>(w_o, woT, 4096, 4096, 4096);

    gemm_bt_128<0><<<dim3(1536 / 128, 16), 256, 0, stream>>>(hid_b, wqaT, q_a, 2048, 1536, 4096);
    gemm_bt_128<0><<<dim3(640 / 128, 16), 256, 0, stream>>>(hid_b, wkvaT, kv, 2048, 640, 4096);
    rmsnorm_kernel<<<2048, 256, 0, stream>>>(q_a, g_qa, q_c, 1536, 1536);
    rmsnorm_kernel<<<2048, 256, 0, stream>>>(kv, g_kva, k_c, 512, 640);
    rope_k_kernel<<<2048 * 32 / 256, 256, 0, stream>>>(kv, cos_t, sin_t, k_rope);
    gemm_bt_128<1><<<dim3(6144 / 128, 16), 256, 0, stream>>>(q_c, wqbT, q_buf, 2048, 6144, 1536);
    rope_scale_q_kernel<<<2048, 256, 0, stream>>>(q_buf, cos_t, sin_t);
    gemm_bt_128<1><<<dim3(8192 / 128, 16), 256, 0, stream>>>(k_c, wkvbT, kst, 2048, 8192, 512);
    transpose_v_kernel<<<1024, 256, 0, stream>>>(kst, V_T);
    attn2_kernel<<<1024, 256, 0, stream>>>(q_buf, kst, k_rope, V_T, attn_out);
    gemm_bt_128<0><<<dim3(4096 / 128, 16), 256, 0, stream>>>(attn_out, woT, out, 2048, 4096, 4096);
}